// Round 12
// baseline (518.767 us; speedup 1.0000x reference)
//
#include <hip/hip_runtime.h>
#include <math.h>

#define MBS   64
#define QLENS 20
#define EMBS  32
#define QVSS  128
#define ANSS  10
#define CHS   24
#define NOBJS 64
#define GS    256

typedef __attribute__((ext_vector_type(8))) short short8;
typedef __attribute__((ext_vector_type(4))) float f32x4;
typedef __attribute__((ext_vector_type(16))) float f32x16;

__device__ __forceinline__ unsigned short f2bf(float f) {
  unsigned u = __float_as_uint(f);
  u += 0x7fffu + ((u >> 16) & 1u);
  return (unsigned short)(u >> 16);
}
__device__ __forceinline__ float sigm(float x) { return 1.0f / (1.0f + expf(-x)); }

// ---------------- prep: g-weights f32->bf16 [48][2][256][8] + g1w transpose ----------------
__global__ __launch_bounds__(256) void prep_k(const float* __restrict__ g2w,
                                              const float* __restrict__ g3w,
                                              const float* __restrict__ g4w,
                                              unsigned short* __restrict__ wbf,
                                              const float* __restrict__ g1w,
                                              float* __restrict__ g1wT) {
  int bidx = blockIdx.x;
  if (bidx < 768) {
    int idx = bidx * 256 + threadIdx.x;              // 3*65536
    int l = idx >> 16, r = idx & 65535;
    int kt = r >> 12;
    int rem = r & 4095;
    int kh = rem >> 11;
    int n = (rem >> 3) & 255;
    int e = rem & 7;
    const float* src = (l == 0) ? g2w : ((l == 1) ? g3w : g4w);
    wbf[idx] = f2bf(src[n * 256 + kt * 16 + kh * 8 + e]);
  } else {
    int idx = (bidx - 768) * 256 + threadIdx.x;      // 180*256
    int f = idx >> 8, n = idx & 255;
    g1wT[f * 256 + n] = g1w[n * 180 + f];
  }
}

// ---------------- fused embed+proj + sequential LSTM, one block per batch ----------------
__global__ __launch_bounds__(512) void lstm_k(const int* __restrict__ question,
                                              const float* __restrict__ emb,
                                              const float* __restrict__ wih,
                                              const float* __restrict__ bih,
                                              const float* __restrict__ bhh,
                                              const float* __restrict__ whh,
                                              float* __restrict__ qvec) {
  int b = blockIdx.x;
  int gt = threadIdx.x;                               // 0..511
  __shared__ float h[QVSS];
  __shared__ float gates[4 * QVSS];
  __shared__ int toks[QLENS];
  float w[QVSS];
#pragma unroll
  for (int k = 0; k < QVSS; ++k) w[k] = whh[gt * QVSS + k];
  float wi[EMBS];
#pragma unroll
  for (int k = 0; k < EMBS; ++k) wi[k] = wih[gt * EMBS + k];
  float bb = bih[gt] + bhh[gt];
  if (gt < QLENS) toks[gt] = question[b * QLENS + gt];
  float c = 0.0f;
  if (gt < QVSS) h[gt] = 0.0f;
  __syncthreads();
  float xp[QLENS];
#pragma unroll
  for (int t = 0; t < QLENS; ++t) {
    const float* e = emb + toks[t] * EMBS;
    float a = bb;
#pragma unroll
    for (int k = 0; k < EMBS; ++k) a += wi[k] * e[k];
    xp[t] = a;
  }
  for (int t = 0; t < QLENS; ++t) {
    float acc = xp[t];
#pragma unroll
    for (int k4 = 0; k4 < QVSS / 4; ++k4) {           // float4 LDS reads
      float4 hv = *reinterpret_cast<const float4*>(&h[k4 * 4]);
      acc += w[k4 * 4 + 0] * hv.x + w[k4 * 4 + 1] * hv.y
           + w[k4 * 4 + 2] * hv.z + w[k4 * 4 + 3] * hv.w;
    }
    gates[gt] = acc;
    __syncthreads();
    if (gt < QVSS) {
      float ig = gates[gt];
      float fg = gates[QVSS + gt];
      float gg = gates[2 * QVSS + gt];
      float og = gates[3 * QVSS + gt];
      c = sigm(fg) * c + sigm(ig) * tanhf(gg);
      h[gt] = sigm(og) * tanhf(c);
    }
    __syncthreads();
  }
  if (gt < QVSS) qvec[b * QVSS + gt] = h[gt];
}

// ---------------- direct conv (stride2 pad1 3x3), 4 outputs/thread ----------------
template <int CIN, int H>
__global__ __launch_bounds__(256) void conv_k(const float* __restrict__ x,
                                              const float* __restrict__ w,
                                              const float* __restrict__ bias,
                                              float* __restrict__ y) {
  const int OH = H / 2, GW = OH / 4;
  __shared__ float4 swp[CHS * CIN * 3];
  __shared__ float sb[CHS];
  for (int i = threadIdx.x; i < CHS * CIN * 3; i += 256) {
    int kh = i % 3, ci = (i / 3) % CIN, co = i / (3 * CIN);
    const float* wp = w + (co * CIN + ci) * 9 + kh * 3;
    swp[i] = make_float4(wp[0], wp[1], wp[2], 0.0f);
  }
  if (threadIdx.x < CHS) sb[threadIdx.x] = bias[threadIdx.x];
  __syncthreads();
  int idx = blockIdx.x * 256 + threadIdx.x;           // 64*24*OH*GW, exact grid
  int g = idx % GW;
  int oh = (idx / GW) % OH;
  int co = (idx / (GW * OH)) % CHS;
  int b  = idx / (CHS * OH * GW);
  float acc0 = sb[co], acc1 = acc0, acc2 = acc0, acc3 = acc0;
  const float* xb = x + b * CIN * H * H;
  const float4* wrow = swp + co * CIN * 3;
  bool left = (g > 0);
#pragma unroll
  for (int kh = 0; kh < 3; ++kh) {
    int ih = oh * 2 - 1 + kh;
    if (ih < 0 || ih >= H) continue;
    for (int ci = 0; ci < CIN; ++ci) {
      const float* row = xb + (ci * H + ih) * H + 8 * g;
      float4 v1 = *(const float4*)(row);
      float4 v2 = *(const float4*)(row + 4);
      float am1 = left ? row[-1] : 0.0f;              // zero-pad at iw = -1
      float4 wv = wrow[ci * 3 + kh];
      acc0 = fmaf(wv.x, am1,  acc0); acc0 = fmaf(wv.y, v1.x, acc0); acc0 = fmaf(wv.z, v1.y, acc0);
      acc1 = fmaf(wv.x, v1.y, acc1); acc1 = fmaf(wv.y, v1.z, acc1); acc1 = fmaf(wv.z, v1.w, acc1);
      acc2 = fmaf(wv.x, v1.w, acc2); acc2 = fmaf(wv.y, v2.x, acc2); acc2 = fmaf(wv.z, v2.y, acc2);
      acc3 = fmaf(wv.x, v2.y, acc3); acc3 = fmaf(wv.y, v2.z, acc3); acc3 = fmaf(wv.z, v2.w, acc3);
    }
  }
  float4 outv = make_float4(acc0, acc1, acc2, acc3);
  *(float4*)(y + ((b * CHS + co) * OH + oh) * OH + 4 * g) = outv;
}

// ---------------- BN stats: per (channel, sub-range) block, few atomics ----------------
__global__ __launch_bounds__(256) void stats_k(const float* __restrict__ y,
                                               float* __restrict__ st,
                                               int HW, int SUB) {
  int c = blockIdx.x / SUB, sub = blockIdx.x % SUB;
  int bpb = MBS / SUB;
  float s = 0.0f, s2 = 0.0f;
  for (int b = sub * bpb; b < (sub + 1) * bpb; ++b) {
    const float* p = y + (b * CHS + c) * HW;
    for (int i = threadIdx.x * 4; i < HW; i += 1024) {
      float4 v = *reinterpret_cast<const float4*>(p + i);
      s  += v.x + v.y + v.z + v.w;
      s2 += v.x * v.x + v.y * v.y + v.z * v.z + v.w * v.w;
    }
  }
#pragma unroll
  for (int off = 1; off < 64; off <<= 1) {
    s  += __shfl_xor(s, off);
    s2 += __shfl_xor(s2, off);
  }
  __shared__ float rs[4], rs2[4];
  int w = threadIdx.x >> 6;
  if ((threadIdx.x & 63) == 0) { rs[w] = s; rs2[w] = s2; }
  __syncthreads();
  if (threadIdx.x == 0) {
    atomicAdd(&st[c * 2 + 0], rs[0] + rs[1] + rs[2] + rs[3]);
    atomicAdd(&st[c * 2 + 1], rs2[0] + rs2[1] + rs2[2] + rs2[3]);
  }
}

// ---------------- BN apply + relu, in place, float4 ----------------
__global__ __launch_bounds__(256) void bn_k(float* __restrict__ y,
                                            const float* __restrict__ st,
                                            const float* __restrict__ g,
                                            const float* __restrict__ beta,
                                            int HW, float inv_cnt) {
  int i4 = (blockIdx.x * 256 + threadIdx.x) * 4;
  int co = (i4 / HW) % CHS;
  float m = st[co * 2 + 0] * inv_cnt;
  float v = st[co * 2 + 1] * inv_cnt - m * m;
  float r = rsqrtf(v + 1e-5f) * g[co];
  float t = beta[co] - m * r;
  float4 vv = *(float4*)(y + i4);
  vv.x = fmaxf(fmaf(vv.x, r, t), 0.0f);
  vv.y = fmaxf(fmaf(vv.y, r, t), 0.0f);
  vv.z = fmaxf(fmaf(vv.z, r, t), 0.0f);
  vv.w = fmaxf(fmaf(vv.w, r, t), 0.0f);
  *(float4*)(y + i4) = vv;
}

// ---------------- fused bn4 + object projections + question projection ----------------
__global__ __launch_bounds__(256) void pre_k(const float* __restrict__ x4raw,
                                             const float* __restrict__ st,
                                             const float* __restrict__ g,
                                             const float* __restrict__ beta,
                                             const float* __restrict__ g1wT,
                                             const float* __restrict__ g1b,
                                             const float* __restrict__ qvec,
                                             float* __restrict__ pre_i,
                                             float* __restrict__ pre_j,
                                             float* __restrict__ pre_q) {
  int bo = blockIdx.x;                                // 4096 obj blocks + 64 q blocks
  int n = threadIdx.x;                                // 256
  __shared__ float sm[QVSS];
  if (bo < 4096) {
    int b = bo >> 6, o = bo & 63;
    if (n < CHS) {
      float m = st[n * 2 + 0] * (1.0f / 4096.0f);
      float v = st[n * 2 + 1] * (1.0f / 4096.0f) - m * m;
      float xv = x4raw[(b * CHS + n) * NOBJS + o];
      sm[n] = fmaxf((xv - m) * rsqrtf(v + 1e-5f) * g[n] + beta[n], 0.0f);
    }
    if (n == 24) sm[24] = (float)(o / 8 - 2) * 0.5f;
    if (n == 25) sm[25] = (float)(o % 8 - 2) * 0.5f;
    __syncthreads();
    float ai = 0.0f, aj = 0.0f;
#pragma unroll
    for (int f = 0; f < 26; ++f) {
      ai += g1wT[f * 256 + n] * sm[f];
      aj += g1wT[(26 + f) * 256 + n] * sm[f];
    }
    pre_i[bo * GS + n] = ai;
    pre_j[bo * GS + n] = aj;
  } else {
    int b = bo - 4096;
    if (n < QVSS) sm[n] = qvec[b * QVSS + n];
    __syncthreads();
    float a = g1b[n];
#pragma unroll
    for (int k = 0; k < QVSS; ++k) a += g1wT[(52 + k) * 256 + n] * sm[k];
    pre_q[b * GS + n] = a;
  }
}

// ---------------- fused relational MLP: 32x32x16 MFMA, 128-row blocks ----------------
// block = (b, j-PAIR): 128 rows (2 j-values) x 256 feats, 8 waves x (128 rows x 32 cols).
// Halves B L2 traffic (each block reads the 384KB weight set once for 2x the work)
// and halves barrier count vs 64-row blocks.
// A (h): 128 rows x 512 B LDS (64KB), byte ^= (row&31)<<4 (conflict-free, verified).
// B: global -> VGPR, depth-2 rotating prefetch (lead ~2 iters x ~128cy wall >= L2 lat).
// Budget: 64 AGPR acc + pa[2]=8 + A transients 16 + addr ~15 ~= 105 < 128 cap (512,4).
// Tripwire: FETCH >100MB in profile => spilled => revert (r8 lesson).
__global__ __launch_bounds__(512, 4) void rel_k(const float* __restrict__ pre_i,
                                                const float* __restrict__ pre_j,
                                                const float* __restrict__ pre_q,
                                                const unsigned short* __restrict__ wbf,
                                                const float* __restrict__ g2b,
                                                const float* __restrict__ g3b,
                                                const float* __restrict__ g4b,
                                                float* __restrict__ xpart) {
  __shared__ short8 hb8[4096];                        // 128 rows x 512 B = 64 KB
  char* hb = (char*)hb8;
  int bid = blockIdx.x;                               // 2048
  int b = bid >> 5, jp = bid & 31;
  int tid = threadIdx.x;
  int w = tid >> 6, lane = tid & 63;                  // w = 0..7 (col slice)
  int l31 = lane & 31, lh = lane >> 5;

  const short8* Wt = (const short8*)wbf;              // 48 chunks x [2 kh][256 n] pieces
  const int nA = w * 32 + l31;                        // wave's 32-col slice
  const int pOff = lh * 256 + nA;                     // piece offset within chunk

  // depth-2 B prefetch: chunks 0,1 issued before phase 0
  short8 pa[2];
  pa[0] = Wt[pOff];
  pa[1] = Wt[512 + pOff];

  // phase 0: h0 = relu(pre_j + pre_i + pre_q); 512 thr: 1 row each, 64-col quarter
  {
    int r = tid & 127, kc = tid >> 7;                 // kc = 0..3
    const float* pj = pre_j + (b * 64 + jp * 2 + (r >> 6)) * GS;
    const float* pi = pre_i + (b * 64 + (r & 63)) * GS;
    const float* pq = pre_q + b * GS;
    int rowbase = r * 512;
    int sw = (r & 31) << 4;
#pragma unroll
    for (int kk = 0; kk < 8; ++kk) {
      int n0 = kc * 64 + kk * 8;
      float4 va  = *(const float4*)(pi + n0);
      float4 va2 = *(const float4*)(pi + n0 + 4);
      float4 vj  = *(const float4*)(pj + n0);
      float4 vj2 = *(const float4*)(pj + n0 + 4);
      float4 vq  = *(const float4*)(pq + n0);
      float4 vq2 = *(const float4*)(pq + n0 + 4);
      short8 pack;
      pack[0] = (short)f2bf(fmaxf(va.x  + vj.x  + vq.x,  0.0f));
      pack[1] = (short)f2bf(fmaxf(va.y  + vj.y  + vq.y,  0.0f));
      pack[2] = (short)f2bf(fmaxf(va.z  + vj.z  + vq.z,  0.0f));
      pack[3] = (short)f2bf(fmaxf(va.w  + vj.w  + vq.w,  0.0f));
      pack[4] = (short)f2bf(fmaxf(va2.x + vj2.x + vq2.x, 0.0f));
      pack[5] = (short)f2bf(fmaxf(va2.y + vj2.y + vq2.y, 0.0f));
      pack[6] = (short)f2bf(fmaxf(va2.z + vj2.z + vq2.z, 0.0f));
      pack[7] = (short)f2bf(fmaxf(va2.w + vj2.w + vq2.w, 0.0f));
      *(short8*)(hb + rowbase + ((n0 * 2) ^ sw)) = pack;
    }
  }
  asm volatile("s_waitcnt lgkmcnt(0)" ::: "memory");
  __builtin_amdgcn_s_barrier();
  __builtin_amdgcn_sched_barrier(0);

  const int rA0 = l31 * 512;                          // rows 0..31   (j0)
  const int rA1 = rA0 + 32 * 512;                     // rows 32..63  (j0)
  const int rA2 = rA0 + 64 * 512;                     // rows 64..95  (j1)
  const int rA3 = rA0 + 96 * 512;                     // rows 96..127 (j1)
  const int swA = l31 << 4;

#pragma unroll 1
  for (int L = 0; L < 3; ++L) {
    const float* bias = (L == 0) ? g2b : ((L == 1) ? g3b : g4b);
    float biasA = bias[nA];
    f32x16 acc0 = {}, acc1 = {}, acc2 = {}, acc3 = {};
#pragma unroll
    for (int kt = 0; kt < 16; ++kt) {
      int colb = (kt * 32 + lh * 16) ^ swA;
      short8 a0 = *(const short8*)(hb + rA0 + colb);
      short8 a1 = *(const short8*)(hb + rA1 + colb);
      short8 a2 = *(const short8*)(hb + rA2 + colb);
      short8 a3 = *(const short8*)(hb + rA3 + colb);
      int pc = L * 16 + kt + 2;                       // crosses layers seamlessly
      pc = (pc < 47) ? pc : 47;                       // tail clamp (harmless L2 re-hit)
      short8 nb = Wt[pc * 512 + pOff];
      acc0 = __builtin_amdgcn_mfma_f32_32x32x16_bf16(a0, pa[kt & 1], acc0, 0, 0, 0);
      acc1 = __builtin_amdgcn_mfma_f32_32x32x16_bf16(a1, pa[kt & 1], acc1, 0, 0, 0);
      acc2 = __builtin_amdgcn_mfma_f32_32x32x16_bf16(a2, pa[kt & 1], acc2, 0, 0, 0);
      acc3 = __builtin_amdgcn_mfma_f32_32x32x16_bf16(a3, pa[kt & 1], acc3, 0, 0, 0);
      pa[kt & 1] = nb;
    }
    // all waves done READING h(L) before anyone rewrites hb
    asm volatile("s_waitcnt lgkmcnt(0)" ::: "memory");
    __builtin_amdgcn_s_barrier();
    __builtin_amdgcn_sched_barrier(0);
    if (L < 2) {
#pragma unroll
      for (int reg = 0; reg < 16; ++reg) {
        int rr = (reg & 3) + 8 * (reg >> 2) + 4 * lh; // 0..31
        int swr = rr << 4;                            // (row&31)<<4, same for all 4 rows
        unsigned short v0 = f2bf(fmaxf(acc0[reg] + biasA, 0.0f));
        unsigned short v1 = f2bf(fmaxf(acc1[reg] + biasA, 0.0f));
        unsigned short v2 = f2bf(fmaxf(acc2[reg] + biasA, 0.0f));
        unsigned short v3 = f2bf(fmaxf(acc3[reg] + biasA, 0.0f));
        *(unsigned short*)(hb + rr * 512        + ((nA * 2) ^ swr)) = v0;
        *(unsigned short*)(hb + (32 + rr) * 512 + ((nA * 2) ^ swr)) = v1;
        *(unsigned short*)(hb + (64 + rr) * 512 + ((nA * 2) ^ swr)) = v2;
        *(unsigned short*)(hb + (96 + rr) * 512 + ((nA * 2) ^ swr)) = v3;
      }
      asm volatile("s_waitcnt lgkmcnt(0)" ::: "memory");
      __builtin_amdgcn_s_barrier();                   // h(L+1) visible
      __builtin_amdgcn_sched_barrier(0);
    } else {
      // per-j column sums: acc0/1 -> j0, acc2/3 -> j1
      float s01 = 0.0f, s23 = 0.0f;
#pragma unroll
      for (int reg = 0; reg < 16; ++reg) {
        s01 += fmaxf(acc0[reg] + biasA, 0.0f) + fmaxf(acc1[reg] + biasA, 0.0f);
        s23 += fmaxf(acc2[reg] + biasA, 0.0f) + fmaxf(acc3[reg] + biasA, 0.0f);
      }
      s01 += __shfl_xor(s01, 32);
      s23 += __shfl_xor(s23, 32);
      float* fs = (float*)hb;                         // reads done (barrier above)
      if (lh == 0) {
        fs[nA] = s01;
        fs[GS + nA] = s23;
      }
      asm volatile("s_waitcnt lgkmcnt(0)" ::: "memory");
      __builtin_amdgcn_s_barrier();
      __builtin_amdgcn_sched_barrier(0);
      xpart[(b * 64 + jp * 2) * GS + tid] = fs[tid];  // 512 floats = both j rows
    }
  }
}

// ---------------- final: reduce xpart over j + f-MLP + log_softmax ----------------
__global__ __launch_bounds__(256) void final_k(const float* __restrict__ xpart,
                                               const float* __restrict__ f1w,
                                               const float* __restrict__ f1b,
                                               const float* __restrict__ f2w,
                                               const float* __restrict__ f2b,
                                               const float* __restrict__ f3w,
                                               const float* __restrict__ f3b,
                                               float* __restrict__ out) {
  int b = blockIdx.x, n = threadIdx.x;
  __shared__ float s0[GS], s1[GS], sl[16];
  float xs = 0.0f;
  for (int j = 0; j < 64; ++j) xs += xpart[(b * 64 + j) * GS + n];
  s0[n] = xs;
  __syncthreads();
  float a = f1b[n];
  {
    const float4* wr = (const float4*)(f1w + n * GS);
    for (int k = 0; k < GS / 4; ++k) {
      float4 wv = wr[k];
      a += wv.x * s0[k * 4] + wv.y * s0[k * 4 + 1] + wv.z * s0[k * 4 + 2] + wv.w * s0[k * 4 + 3];
    }
  }
  s1[n] = fmaxf(a, 0.0f);
  __syncthreads();
  a = f2b[n];
  {
    const float4* wr = (const float4*)(f2w + n * GS);
    for (int k = 0; k < GS / 4; ++k) {
      float4 wv = wr[k];
      a += wv.x * s1[k * 4] + wv.y * s1[k * 4 + 1] + wv.z * s1[k * 4 + 2] + wv.w * s1[k * 4 + 3];
    }
  }
  s0[n] = fmaxf(a, 0.0f);
  __syncthreads();
  if (n < ANSS) {
    a = f3b[n];
    const float4* wr = (const float4*)(f3w + n * GS);
    for (int k = 0; k < GS / 4; ++k) {
      float4 wv = wr[k];
      a += wv.x * s0[k * 4] + wv.y * s0[k * 4 + 1] + wv.z * s0[k * 4 + 2] + wv.w * s0[k * 4 + 3];
    }
    sl[n] = a;
  }
  __syncthreads();
  if (n == 0) {
    float m = -1e30f;
    for (int i = 0; i < ANSS; ++i) m = fmaxf(m, sl[i]);
    float s = 0.0f;
    for (int i = 0; i < ANSS; ++i) s += expf(sl[i] - m);
    sl[12] = m + logf(s);
  }
  __syncthreads();
  if (n < ANSS) out[b * ANSS + n] = sl[n] - sl[12];
}

extern "C" void kernel_launch(void* const* d_in, const int* in_sizes, int n_in,
                              void* d_out, int out_size, void* d_ws, size_t ws_size,
                              hipStream_t stream) {
  const float* image = (const float*)d_in[0];
  const int*   question = (const int*)d_in[1];
  const float* emb = (const float*)d_in[2];
  const float* wih = (const float*)d_in[3];
  const float* whh = (const float*)d_in[4];
  const float* bih = (const float*)d_in[5];
  const float* bhh = (const float*)d_in[6];
  const float* c1w = (const float*)d_in[7];
  const float* c1b = (const float*)d_in[8];
  const float* bn1g = (const float*)d_in[9];
  const float* bn1b = (const float*)d_in[10];
  const float* c2w = (const float*)d_in[11];
  const float* c2b = (const float*)d_in[12];
  const float* bn2g = (const float*)d_in[13];
  const float* bn2b = (const float*)d_in[14];
  const float* c3w = (const float*)d_in[15];
  const float* c3b = (const float*)d_in[16];
  const float* bn3g = (const float*)d_in[17];
  const float* bn3b = (const float*)d_in[18];
  const float* c4w = (const float*)d_in[19];
  const float* c4b = (const float*)d_in[20];
  const float* bn4g = (const float*)d_in[21];
  const float* bn4b = (const float*)d_in[22];
  const float* g1w = (const float*)d_in[23];
  const float* g1b = (const float*)d_in[24];
  const float* g2w = (const float*)d_in[25];
  const float* g2b = (const float*)d_in[26];
  const float* g3w = (const float*)d_in[27];
  const float* g3b = (const float*)d_in[28];
  const float* g4w = (const float*)d_in[29];
  const float* g4b = (const float*)d_in[30];
  const float* f1w = (const float*)d_in[31];
  const float* f1b = (const float*)d_in[32];
  const float* f2w = (const float*)d_in[33];
  const float* f2b = (const float*)d_in[34];
  const float* f3w = (const float*)d_in[35];
  const float* f3b = (const float*)d_in[36];
  float* out = (float*)d_out;

  float* wsf = (float*)d_ws;
  float* arenaA = wsf;                                // 6,291,456 f (y1/y3; later xpart)
  float* arenaB = wsf + 6291456;                      // 1,572,864 f (y2/y4)
  float* qvec   = wsf + 8519680;                      // 8,192 f
  float* pre_i  = wsf + 8527872;                      // 1,048,576 f
  float* pre_j  = wsf + 9576448;                      // 1,048,576 f
  float* pre_q  = wsf + 10625024;                     // 16,384 f
  float* stats  = wsf + 10657792;                     // 256 f (4 layers x 24 x 2)
  unsigned short* wbf = (unsigned short*)(wsf + 10658048); // 196,608 bf16
  float* g1wT   = wsf + 10756352;                     // 46,080 f
  float* xpart  = arenaA;                             // reuse: convs done before rel_k

  hipMemsetAsync(stats, 0, 256 * sizeof(float), stream);

  prep_k<<<948, 256, 0, stream>>>(g2w, g3w, g4w, wbf, g1w, g1wT);
  lstm_k<<<64, 512, 0, stream>>>(question, emb, wih, bih, bhh, whh, qvec);

  conv_k<3, 128><<<6144, 256, 0, stream>>>(image, c1w, c1b, arenaA);
  stats_k<<<24 * 16, 256, 0, stream>>>(arenaA, stats + 0, 4096, 16);
  bn_k<<<6144, 256, 0, stream>>>(arenaA, stats + 0, bn1g, bn1b, 4096, 1.0f / 262144.0f);

  conv_k<24, 64><<<1536, 256, 0, stream>>>(arenaA, c2w, c2b, arenaB);
  stats_k<<<24 * 16, 256, 0, stream>>>(arenaB, stats + 48, 1024, 16);
  bn_k<<<1536, 256, 0, stream>>>(arenaB, stats + 48, bn2g, bn2b, 1024, 1.0f / 65536.0f);

  conv_k<24, 32><<<384, 256, 0, stream>>>(arenaB, c3w, c3b, arenaA);
  stats_k<<<24 * 4, 256, 0, stream>>>(arenaA, stats + 96, 256, 4);
  bn_k<<<384, 256, 0, stream>>>(arenaA, stats + 96, bn3g, bn3b, 256, 1.0f / 16384.0f);

  conv_k<24, 16><<<96, 256, 0, stream>>>(arenaA, c4w, c4b, arenaB);
  stats_k<<<24, 256, 0, stream>>>(arenaB, stats + 144, 64, 1);

  pre_k<<<4096 + 64, 256, 0, stream>>>(arenaB, stats + 144, bn4g, bn4b, g1wT, g1b, qvec,
                                       pre_i, pre_j, pre_q);

  rel_k<<<2048, 512, 0, stream>>>(pre_i, pre_j, pre_q, wbf, g2b, g3b, g4b, xpart);

  final_k<<<64, 256, 0, stream>>>(xpart, f1w, f1b, f2w, f2b, f3w, f3b, out);
}

// Round 13
// 393.019 us; speedup vs baseline: 1.3200x; 1.3200x over previous
//
#include <hip/hip_runtime.h>
#include <math.h>

#define MBS   64
#define QLENS 20
#define EMBS  32
#define QVSS  128
#define ANSS  10
#define CHS   24
#define NOBJS 64
#define GS    256

typedef __attribute__((ext_vector_type(8))) short short8;
typedef __attribute__((ext_vector_type(4))) float f32x4;
typedef __attribute__((ext_vector_type(16))) float f32x16;

__device__ __forceinline__ unsigned short f2bf(float f) {
  unsigned u = __float_as_uint(f);
  u += 0x7fffu + ((u >> 16) & 1u);
  return (unsigned short)(u >> 16);
}
__device__ __forceinline__ float sigm(float x) { return 1.0f / (1.0f + expf(-x)); }

// ---------------- prep: g-weights f32->bf16 [48][2][256][8] + g1w transpose ----------------
__global__ __launch_bounds__(256) void prep_k(const float* __restrict__ g2w,
                                              const float* __restrict__ g3w,
                                              const float* __restrict__ g4w,
                                              unsigned short* __restrict__ wbf,
                                              const float* __restrict__ g1w,
                                              float* __restrict__ g1wT) {
  int bidx = blockIdx.x;
  if (bidx < 768) {
    int idx = bidx * 256 + threadIdx.x;              // 3*65536
    int l = idx >> 16, r = idx & 65535;
    int kt = r >> 12;
    int rem = r & 4095;
    int kh = rem >> 11;
    int n = (rem >> 3) & 255;
    int e = rem & 7;
    const float* src = (l == 0) ? g2w : ((l == 1) ? g3w : g4w);
    wbf[idx] = f2bf(src[n * 256 + kt * 16 + kh * 8 + e]);
  } else {
    int idx = (bidx - 768) * 256 + threadIdx.x;      // 180*256
    int f = idx >> 8, n = idx & 255;
    g1wT[f * 256 + n] = g1w[n * 180 + f];
  }
}

// ---------------- fused embed+proj + sequential LSTM, one block per batch ----------------
__global__ __launch_bounds__(512) void lstm_k(const int* __restrict__ question,
                                              const float* __restrict__ emb,
                                              const float* __restrict__ wih,
                                              const float* __restrict__ bih,
                                              const float* __restrict__ bhh,
                                              const float* __restrict__ whh,
                                              float* __restrict__ qvec) {
  int b = blockIdx.x;
  int gt = threadIdx.x;                               // 0..511
  __shared__ float h[QVSS];
  __shared__ float gates[4 * QVSS];
  __shared__ int toks[QLENS];
  float w[QVSS];
#pragma unroll
  for (int k = 0; k < QVSS; ++k) w[k] = whh[gt * QVSS + k];
  float wi[EMBS];
#pragma unroll
  for (int k = 0; k < EMBS; ++k) wi[k] = wih[gt * EMBS + k];
  float bb = bih[gt] + bhh[gt];
  if (gt < QLENS) toks[gt] = question[b * QLENS + gt];
  float c = 0.0f;
  if (gt < QVSS) h[gt] = 0.0f;
  __syncthreads();
  float xp[QLENS];
#pragma unroll
  for (int t = 0; t < QLENS; ++t) {
    const float* e = emb + toks[t] * EMBS;
    float a = bb;
#pragma unroll
    for (int k = 0; k < EMBS; ++k) a += wi[k] * e[k];
    xp[t] = a;
  }
  for (int t = 0; t < QLENS; ++t) {
    float acc = xp[t];
#pragma unroll
    for (int k4 = 0; k4 < QVSS / 4; ++k4) {           // float4 LDS reads
      float4 hv = *reinterpret_cast<const float4*>(&h[k4 * 4]);
      acc += w[k4 * 4 + 0] * hv.x + w[k4 * 4 + 1] * hv.y
           + w[k4 * 4 + 2] * hv.z + w[k4 * 4 + 3] * hv.w;
    }
    gates[gt] = acc;
    __syncthreads();
    if (gt < QVSS) {
      float ig = gates[gt];
      float fg = gates[QVSS + gt];
      float gg = gates[2 * QVSS + gt];
      float og = gates[3 * QVSS + gt];
      c = sigm(fg) * c + sigm(ig) * tanhf(gg);
      h[gt] = sigm(og) * tanhf(c);
    }
    __syncthreads();
  }
  if (gt < QVSS) qvec[b * QVSS + gt] = h[gt];
}

// ---------------- direct conv (stride2 pad1 3x3), 8 outputs/thread (2 co x 4 ow) ----------------
// Input loads (2 float4 + 1 edge scalar) are shared across the co-pair: 3 loads feed 24 FMA.
template <int CIN, int H>
__global__ __launch_bounds__(256) void conv_k(const float* __restrict__ x,
                                              const float* __restrict__ w,
                                              const float* __restrict__ bias,
                                              float* __restrict__ y) {
  const int OH = H / 2, GW = OH / 4, CP = CHS / 2;
  __shared__ float4 swp[CHS * CIN * 3];
  __shared__ float sb[CHS];
  for (int i = threadIdx.x; i < CHS * CIN * 3; i += 256) {
    int kh = i % 3, ci = (i / 3) % CIN, co = i / (3 * CIN);
    const float* wp = w + (co * CIN + ci) * 9 + kh * 3;
    swp[i] = make_float4(wp[0], wp[1], wp[2], 0.0f);
  }
  if (threadIdx.x < CHS) sb[threadIdx.x] = bias[threadIdx.x];
  __syncthreads();
  int idx = blockIdx.x * 256 + threadIdx.x;           // 64*12*OH*GW, exact grid
  int g = idx % GW;
  int oh = (idx / GW) % OH;
  int cp = (idx / (GW * OH)) % CP;
  int b  = idx / (CP * OH * GW);
  int co0 = cp * 2, co1 = co0 + 1;
  float a00 = sb[co0], a01 = a00, a02 = a00, a03 = a00;
  float a10 = sb[co1], a11 = a10, a12 = a10, a13 = a10;
  const float* xb = x + b * CIN * H * H;
  const float4* w0 = swp + co0 * CIN * 3;
  const float4* w1 = swp + co1 * CIN * 3;
  bool left = (g > 0);
#pragma unroll
  for (int kh = 0; kh < 3; ++kh) {
    int ih = oh * 2 - 1 + kh;
    if (ih < 0 || ih >= H) continue;
    for (int ci = 0; ci < CIN; ++ci) {
      const float* row = xb + (ci * H + ih) * H + 8 * g;
      float4 v1 = *(const float4*)(row);
      float4 v2 = *(const float4*)(row + 4);
      float am1 = left ? row[-1] : 0.0f;              // zero-pad at iw = -1
      float4 wa = w0[ci * 3 + kh];
      float4 wb = w1[ci * 3 + kh];
      a00 = fmaf(wa.x, am1,  a00); a00 = fmaf(wa.y, v1.x, a00); a00 = fmaf(wa.z, v1.y, a00);
      a01 = fmaf(wa.x, v1.y, a01); a01 = fmaf(wa.y, v1.z, a01); a01 = fmaf(wa.z, v1.w, a01);
      a02 = fmaf(wa.x, v1.w, a02); a02 = fmaf(wa.y, v2.x, a02); a02 = fmaf(wa.z, v2.y, a02);
      a03 = fmaf(wa.x, v2.y, a03); a03 = fmaf(wa.y, v2.z, a03); a03 = fmaf(wa.z, v2.w, a03);
      a10 = fmaf(wb.x, am1,  a10); a10 = fmaf(wb.y, v1.x, a10); a10 = fmaf(wb.z, v1.y, a10);
      a11 = fmaf(wb.x, v1.y, a11); a11 = fmaf(wb.y, v1.z, a11); a11 = fmaf(wb.z, v1.w, a11);
      a12 = fmaf(wb.x, v1.w, a12); a12 = fmaf(wb.y, v2.x, a12); a12 = fmaf(wb.z, v2.y, a12);
      a13 = fmaf(wb.x, v2.y, a13); a13 = fmaf(wb.y, v2.z, a13); a13 = fmaf(wb.z, v2.w, a13);
    }
  }
  *(float4*)(y + ((b * CHS + co0) * OH + oh) * OH + 4 * g) = make_float4(a00, a01, a02, a03);
  *(float4*)(y + ((b * CHS + co1) * OH + oh) * OH + 4 * g) = make_float4(a10, a11, a12, a13);
}

// ---------------- BN stats: per (channel, sub-range) block, few atomics ----------------
__global__ __launch_bounds__(256) void stats_k(const float* __restrict__ y,
                                               float* __restrict__ st,
                                               int HW, int SUB) {
  int c = blockIdx.x / SUB, sub = blockIdx.x % SUB;
  int bpb = MBS / SUB;
  float s = 0.0f, s2 = 0.0f;
  for (int b = sub * bpb; b < (sub + 1) * bpb; ++b) {
    const float* p = y + (b * CHS + c) * HW;
    for (int i = threadIdx.x * 4; i < HW; i += 1024) {
      float4 v = *reinterpret_cast<const float4*>(p + i);
      s  += v.x + v.y + v.z + v.w;
      s2 += v.x * v.x + v.y * v.y + v.z * v.z + v.w * v.w;
    }
  }
#pragma unroll
  for (int off = 1; off < 64; off <<= 1) {
    s  += __shfl_xor(s, off);
    s2 += __shfl_xor(s2, off);
  }
  __shared__ float rs[4], rs2[4];
  int w = threadIdx.x >> 6;
  if ((threadIdx.x & 63) == 0) { rs[w] = s; rs2[w] = s2; }
  __syncthreads();
  if (threadIdx.x == 0) {
    atomicAdd(&st[c * 2 + 0], rs[0] + rs[1] + rs[2] + rs[3]);
    atomicAdd(&st[c * 2 + 1], rs2[0] + rs2[1] + rs2[2] + rs2[3]);
  }
}

// ---------------- BN apply + relu, in place, float4 ----------------
__global__ __launch_bounds__(256) void bn_k(float* __restrict__ y,
                                            const float* __restrict__ st,
                                            const float* __restrict__ g,
                                            const float* __restrict__ beta,
                                            int HW, float inv_cnt) {
  int i4 = (blockIdx.x * 256 + threadIdx.x) * 4;
  int co = (i4 / HW) % CHS;
  float m = st[co * 2 + 0] * inv_cnt;
  float v = st[co * 2 + 1] * inv_cnt - m * m;
  float r = rsqrtf(v + 1e-5f) * g[co];
  float t = beta[co] - m * r;
  float4 vv = *(float4*)(y + i4);
  vv.x = fmaxf(fmaf(vv.x, r, t), 0.0f);
  vv.y = fmaxf(fmaf(vv.y, r, t), 0.0f);
  vv.z = fmaxf(fmaf(vv.z, r, t), 0.0f);
  vv.w = fmaxf(fmaf(vv.w, r, t), 0.0f);
  *(float4*)(y + i4) = vv;
}

// ---------------- fused bn4 + object projections + question projection ----------------
__global__ __launch_bounds__(256) void pre_k(const float* __restrict__ x4raw,
                                             const float* __restrict__ st,
                                             const float* __restrict__ g,
                                             const float* __restrict__ beta,
                                             const float* __restrict__ g1wT,
                                             const float* __restrict__ g1b,
                                             const float* __restrict__ qvec,
                                             float* __restrict__ pre_i,
                                             float* __restrict__ pre_j,
                                             float* __restrict__ pre_q) {
  int bo = blockIdx.x;                                // 4096 obj blocks + 64 q blocks
  int n = threadIdx.x;                                // 256
  __shared__ float sm[QVSS];
  if (bo < 4096) {
    int b = bo >> 6, o = bo & 63;
    if (n < CHS) {
      float m = st[n * 2 + 0] * (1.0f / 4096.0f);
      float v = st[n * 2 + 1] * (1.0f / 4096.0f) - m * m;
      float xv = x4raw[(b * CHS + n) * NOBJS + o];
      sm[n] = fmaxf((xv - m) * rsqrtf(v + 1e-5f) * g[n] + beta[n], 0.0f);
    }
    if (n == 24) sm[24] = (float)(o / 8 - 2) * 0.5f;
    if (n == 25) sm[25] = (float)(o % 8 - 2) * 0.5f;
    __syncthreads();
    float ai = 0.0f, aj = 0.0f;
#pragma unroll
    for (int f = 0; f < 26; ++f) {
      ai += g1wT[f * 256 + n] * sm[f];
      aj += g1wT[(26 + f) * 256 + n] * sm[f];
    }
    pre_i[bo * GS + n] = ai;
    pre_j[bo * GS + n] = aj;
  } else {
    int b = bo - 4096;
    if (n < QVSS) sm[n] = qvec[b * QVSS + n];
    __syncthreads();
    float a = g1b[n];
#pragma unroll
    for (int k = 0; k < QVSS; ++k) a += g1wT[(52 + k) * 256 + n] * sm[k];
    pre_q[b * GS + n] = a;
  }
}

// ---------------- fused relational MLP: 32x32x16 MFMA (r11 proven: 143us, no spill) ----------------
// block = (b, j): 64 rows x 256 feats, 8 waves x (64 rows x 32 cols).
// B: global -> VGPR, depth-4 rotating prefetch. A: LDS, 1-kt-ahead register prefetch.
// DO NOT grow acc beyond 2x f32x16: 128-row variants spill at the (512,4) 128-reg cap
// (r8/r12: FETCH 150-500MB scratch traffic) and (512,2) halves occupancy (r7: 176us).
__global__ __launch_bounds__(512, 4) void rel_k(const float* __restrict__ pre_i,
                                                const float* __restrict__ pre_j,
                                                const float* __restrict__ pre_q,
                                                const unsigned short* __restrict__ wbf,
                                                const float* __restrict__ g2b,
                                                const float* __restrict__ g3b,
                                                const float* __restrict__ g4b,
                                                float* __restrict__ xpart) {
  __shared__ short8 hb8[2048];                        // 64 rows x 512 B = 32 KB
  char* hb = (char*)hb8;
  int bid = blockIdx.x;                               // 4096
  int b = bid >> 6, j = bid & 63;
  int tid = threadIdx.x;
  int w = tid >> 6, lane = tid & 63;                  // w = 0..7 (col slice)
  int l31 = lane & 31, lh = lane >> 5;

  const short8* Wt = (const short8*)wbf;              // 48 chunks x [2 kh][256 n] pieces
  const int nA = w * 32 + l31;                        // wave's 32-col slice
  const int pOff = lh * 256 + nA;                     // piece offset within chunk

  // depth-4 B prefetch: chunks 0..3 issued before phase 0 (slot = chunk & 3)
  short8 pa[4];
#pragma unroll
  for (int i = 0; i < 4; ++i) pa[i] = Wt[i * 512 + pOff];

  // phase 0: h0 = relu(pre_j[b,j] + pre_i[b,i] + pre_q[b]); 512 thr: 8 per row
  {
    int r = tid & 63, kc = tid >> 6;
    const float* pj = pre_j + (b * 64 + j) * GS;
    const float* pi = pre_i + (b * 64 + r) * GS;
    const float* pq = pre_q + b * GS;
    int rowbase = r * 512;
    int sw = (r & 31) << 4;
#pragma unroll
    for (int kk = 0; kk < 4; ++kk) {
      int n0 = kc * 32 + kk * 8;
      float4 va  = *(const float4*)(pi + n0);
      float4 va2 = *(const float4*)(pi + n0 + 4);
      float4 vj  = *(const float4*)(pj + n0);
      float4 vj2 = *(const float4*)(pj + n0 + 4);
      float4 vq  = *(const float4*)(pq + n0);
      float4 vq2 = *(const float4*)(pq + n0 + 4);
      short8 pack;
      pack[0] = (short)f2bf(fmaxf(va.x  + vj.x  + vq.x,  0.0f));
      pack[1] = (short)f2bf(fmaxf(va.y  + vj.y  + vq.y,  0.0f));
      pack[2] = (short)f2bf(fmaxf(va.z  + vj.z  + vq.z,  0.0f));
      pack[3] = (short)f2bf(fmaxf(va.w  + vj.w  + vq.w,  0.0f));
      pack[4] = (short)f2bf(fmaxf(va2.x + vj2.x + vq2.x, 0.0f));
      pack[5] = (short)f2bf(fmaxf(va2.y + vj2.y + vq2.y, 0.0f));
      pack[6] = (short)f2bf(fmaxf(va2.z + vj2.z + vq2.z, 0.0f));
      pack[7] = (short)f2bf(fmaxf(va2.w + vj2.w + vq2.w, 0.0f));
      *(short8*)(hb + rowbase + ((n0 * 2) ^ sw)) = pack;
    }
  }
  asm volatile("s_waitcnt lgkmcnt(0)" ::: "memory");
  __builtin_amdgcn_s_barrier();
  __builtin_amdgcn_sched_barrier(0);

  const int rA0 = l31 * 512;
  const int rA1 = (32 + l31) * 512;
  const int swA = l31 << 4;
  const int aCol0 = (lh * 16) ^ swA;                  // kt=0 column byte offset

#pragma unroll 1
  for (int L = 0; L < 3; ++L) {
    const float* bias = (L == 0) ? g2b : ((L == 1) ? g3b : g4b);
    float biasA = bias[nA];
    f32x16 acc0 = {}, acc1 = {};
    // A prologue: fragments for kt = 0
    short8 a0 = *(const short8*)(hb + rA0 + aCol0);
    short8 a1 = *(const short8*)(hb + rA1 + aCol0);
#pragma unroll
    for (int kt = 0; kt < 16; ++kt) {
      short8 c0 = a0, c1 = a1;
      int ktn = (kt < 15) ? kt + 1 : 15;
      int colb = (ktn * 32 + lh * 16) ^ swA;
      a0 = *(const short8*)(hb + rA0 + colb);
      a1 = *(const short8*)(hb + rA1 + colb);
      int pc = L * 16 + kt + 4;
      pc = (pc < 47) ? pc : 47;
      short8 nb = Wt[pc * 512 + pOff];
      acc0 = __builtin_amdgcn_mfma_f32_32x32x16_bf16(c0, pa[kt & 3], acc0, 0, 0, 0);
      acc1 = __builtin_amdgcn_mfma_f32_32x32x16_bf16(c1, pa[kt & 3], acc1, 0, 0, 0);
      pa[kt & 3] = nb;
    }
    // all waves done READING h(L) before anyone rewrites hb
    asm volatile("s_waitcnt lgkmcnt(0)" ::: "memory");
    __builtin_amdgcn_s_barrier();
    __builtin_amdgcn_sched_barrier(0);
    if (L < 2) {
#pragma unroll
      for (int reg = 0; reg < 16; ++reg) {
        int rr = (reg & 3) + 8 * (reg >> 2) + 4 * lh; // 0..31
        int swr = rr << 4;
        unsigned short v0 = f2bf(fmaxf(acc0[reg] + biasA, 0.0f));
        unsigned short v1 = f2bf(fmaxf(acc1[reg] + biasA, 0.0f));
        *(unsigned short*)(hb + rr * 512        + ((nA * 2) ^ swr)) = v0;
        *(unsigned short*)(hb + (32 + rr) * 512 + ((nA * 2) ^ swr)) = v1;
      }
      asm volatile("s_waitcnt lgkmcnt(0)" ::: "memory");
      __builtin_amdgcn_s_barrier();                   // h(L+1) visible
      __builtin_amdgcn_sched_barrier(0);
    } else {
      float sA = 0.0f;
#pragma unroll
      for (int reg = 0; reg < 16; ++reg)
        sA += fmaxf(acc0[reg] + biasA, 0.0f) + fmaxf(acc1[reg] + biasA, 0.0f);
      sA += __shfl_xor(sA, 32);
      float* fs = (float*)hb;
      if (lh == 0) fs[nA] = sA;
      asm volatile("s_waitcnt lgkmcnt(0)" ::: "memory");
      __builtin_amdgcn_s_barrier();
      __builtin_amdgcn_sched_barrier(0);
      if (tid < GS) xpart[bid * GS + tid] = fs[tid];
    }
  }
}

// ---------------- final: reduce xpart over j + f-MLP + log_softmax ----------------
__global__ __launch_bounds__(256) void final_k(const float* __restrict__ xpart,
                                               const float* __restrict__ f1w,
                                               const float* __restrict__ f1b,
                                               const float* __restrict__ f2w,
                                               const float* __restrict__ f2b,
                                               const float* __restrict__ f3w,
                                               const float* __restrict__ f3b,
                                               float* __restrict__ out) {
  int b = blockIdx.x, n = threadIdx.x;
  __shared__ float s0[GS], s1[GS], sl[16];
  float xs = 0.0f;
  for (int j = 0; j < 64; ++j) xs += xpart[(b * 64 + j) * GS + n];
  s0[n] = xs;
  __syncthreads();
  float a = f1b[n];
  {
    const float4* wr = (const float4*)(f1w + n * GS);
    for (int k = 0; k < GS / 4; ++k) {
      float4 wv = wr[k];
      a += wv.x * s0[k * 4] + wv.y * s0[k * 4 + 1] + wv.z * s0[k * 4 + 2] + wv.w * s0[k * 4 + 3];
    }
  }
  s1[n] = fmaxf(a, 0.0f);
  __syncthreads();
  a = f2b[n];
  {
    const float4* wr = (const float4*)(f2w + n * GS);
    for (int k = 0; k < GS / 4; ++k) {
      float4 wv = wr[k];
      a += wv.x * s1[k * 4] + wv.y * s1[k * 4 + 1] + wv.z * s1[k * 4 + 2] + wv.w * s1[k * 4 + 3];
    }
  }
  s0[n] = fmaxf(a, 0.0f);
  __syncthreads();
  if (n < ANSS) {
    a = f3b[n];
    const float4* wr = (const float4*)(f3w + n * GS);
    for (int k = 0; k < GS / 4; ++k) {
      float4 wv = wr[k];
      a += wv.x * s0[k * 4] + wv.y * s0[k * 4 + 1] + wv.z * s0[k * 4 + 2] + wv.w * s0[k * 4 + 3];
    }
    sl[n] = a;
  }
  __syncthreads();
  if (n == 0) {
    float m = -1e30f;
    for (int i = 0; i < ANSS; ++i) m = fmaxf(m, sl[i]);
    float s = 0.0f;
    for (int i = 0; i < ANSS; ++i) s += expf(sl[i] - m);
    sl[12] = m + logf(s);
  }
  __syncthreads();
  if (n < ANSS) out[b * ANSS + n] = sl[n] - sl[12];
}

extern "C" void kernel_launch(void* const* d_in, const int* in_sizes, int n_in,
                              void* d_out, int out_size, void* d_ws, size_t ws_size,
                              hipStream_t stream) {
  const float* image = (const float*)d_in[0];
  const int*   question = (const int*)d_in[1];
  const float* emb = (const float*)d_in[2];
  const float* wih = (const float*)d_in[3];
  const float* whh = (const float*)d_in[4];
  const float* bih = (const float*)d_in[5];
  const float* bhh = (const float*)d_in[6];
  const float* c1w = (const float*)d_in[7];
  const float* c1b = (const float*)d_in[8];
  const float* bn1g = (const float*)d_in[9];
  const float* bn1b = (const float*)d_in[10];
  const float* c2w = (const float*)d_in[11];
  const float* c2b = (const float*)d_in[12];
  const float* bn2g = (const float*)d_in[13];
  const float* bn2b = (const float*)d_in[14];
  const float* c3w = (const float*)d_in[15];
  const float* c3b = (const float*)d_in[16];
  const float* bn3g = (const float*)d_in[17];
  const float* bn3b = (const float*)d_in[18];
  const float* c4w = (const float*)d_in[19];
  const float* c4b = (const float*)d_in[20];
  const float* bn4g = (const float*)d_in[21];
  const float* bn4b = (const float*)d_in[22];
  const float* g1w = (const float*)d_in[23];
  const float* g1b = (const float*)d_in[24];
  const float* g2w = (const float*)d_in[25];
  const float* g2b = (const float*)d_in[26];
  const float* g3w = (const float*)d_in[27];
  const float* g3b = (const float*)d_in[28];
  const float* g4w = (const float*)d_in[29];
  const float* g4b = (const float*)d_in[30];
  const float* f1w = (const float*)d_in[31];
  const float* f1b = (const float*)d_in[32];
  const float* f2w = (const float*)d_in[33];
  const float* f2b = (const float*)d_in[34];
  const float* f3w = (const float*)d_in[35];
  const float* f3b = (const float*)d_in[36];
  float* out = (float*)d_out;

  float* wsf = (float*)d_ws;
  float* arenaA = wsf;                                // 6,291,456 f (y1/y3; later xpart)
  float* arenaB = wsf + 6291456;                      // 1,572,864 f (y2/y4)
  float* qvec   = wsf + 8519680;                      // 8,192 f
  float* pre_i  = wsf + 8527872;                      // 1,048,576 f
  float* pre_j  = wsf + 9576448;                      // 1,048,576 f
  float* pre_q  = wsf + 10625024;                     // 16,384 f
  float* stats  = wsf + 10657792;                     // 256 f (4 layers x 24 x 2)
  unsigned short* wbf = (unsigned short*)(wsf + 10658048); // 196,608 bf16
  float* g1wT   = wsf + 10756352;                     // 46,080 f
  float* xpart  = arenaA;                             // reuse: convs done before rel_k

  hipMemsetAsync(stats, 0, 256 * sizeof(float), stream);

  prep_k<<<948, 256, 0, stream>>>(g2w, g3w, g4w, wbf, g1w, g1wT);
  lstm_k<<<64, 512, 0, stream>>>(question, emb, wih, bih, bhh, whh, qvec);

  conv_k<3, 128><<<3072, 256, 0, stream>>>(image, c1w, c1b, arenaA);
  stats_k<<<24 * 16, 256, 0, stream>>>(arenaA, stats + 0, 4096, 16);
  bn_k<<<6144, 256, 0, stream>>>(arenaA, stats + 0, bn1g, bn1b, 4096, 1.0f / 262144.0f);

  conv_k<24, 64><<<768, 256, 0, stream>>>(arenaA, c2w, c2b, arenaB);
  stats_k<<<24 * 16, 256, 0, stream>>>(arenaB, stats + 48, 1024, 16);
  bn_k<<<1536, 256, 0, stream>>>(arenaB, stats + 48, bn2g, bn2b, 1024, 1.0f / 65536.0f);

  conv_k<24, 32><<<192, 256, 0, stream>>>(arenaB, c3w, c3b, arenaA);
  stats_k<<<24 * 4, 256, 0, stream>>>(arenaA, stats + 96, 256, 4);
  bn_k<<<384, 256, 0, stream>>>(arenaA, stats + 96, bn3g, bn3b, 256, 1.0f / 16384.0f);

  conv_k<24, 16><<<48, 256, 0, stream>>>(arenaA, c4w, c4b, arenaB);
  stats_k<<<24, 256, 0, stream>>>(arenaB, stats + 144, 64, 1);

  pre_k<<<4096 + 64, 256, 0, stream>>>(arenaB, stats + 144, bn4g, bn4b, g1wT, g1b, qvec,
                                       pre_i, pre_j, pre_q);

  rel_k<<<4096, 512, 0, stream>>>(pre_i, pre_j, pre_q, wbf, g2b, g3b, g4b, xpart);

  final_k<<<64, 256, 0, stream>>>(xpart, f1w, f1b, f2w, f2b, f3w, f3b, out);
}